// Round 2
// baseline (669.878 us; speedup 1.0000x reference)
//
#include <hip/hip_runtime.h>

// out[b,c,h,w] = x[b,c, h^3, w^3]  (combined adjacent+interlaced perm = reverse
// each block of 4 on both H and W; 256 % 4 == 0 so no tail handling).
// Flat:  out[e] = in[e ^ 0x303].
// float4: out4[t] = reverse_components(in4[t ^ 0xC0]).
//
// Pure HBM stream: 402.7 MB read + 402.7 MB write -> floor ~128 us @ 6.3 TB/s
// (the harness's own fills measure 6.30-6.37 TB/s on this chip).
//
// Grid-stride, 48 float4/thread (unroll 4 -> 4 independent loads in flight)
// + non-temporal load/store (805 MB stream > 256 MB L3; don't dirty cache).
// 2048 blocks x 256 thr = 8 blocks/CU = 32 waves/CU.
//
// NOTE: __builtin_nontemporal_* rejects HIP_vector_type (float4 is a class);
// use a native ext_vector_type(4) float instead.

#define TPB    256
#define BLOCKS 2048

typedef float f4 __attribute__((ext_vector_type(4)));

__global__ __launch_bounds__(TPB) void dualswitch_kernel(
    const f4* __restrict__ in, f4* __restrict__ out, int iters) {
    const int stride = BLOCKS * TPB;
    int t = blockIdx.x * TPB + threadIdx.x;
    #pragma unroll 4
    for (int i = 0; i < iters; ++i, t += stride) {
        // XOR 0xC0 flips bits 6,7 of t = wave-index bits (lane = bits 0..5):
        // each wave reads one contiguous 1 KiB segment -> fully coalesced.
        const f4 v = __builtin_nontemporal_load(in + (t ^ 0xC0));
        const f4 r = {v.w, v.z, v.y, v.x};      // w ^= 3 inside the float4
        __builtin_nontemporal_store(r, out + t);
    }
}

extern "C" void kernel_launch(void* const* d_in, const int* in_sizes, int n_in,
                              void* d_out, int out_size, void* d_ws, size_t ws_size,
                              hipStream_t stream) {
    const f4* in = (const f4*)d_in[0];
    f4* out = (f4*)d_out;
    const int total4 = out_size / 4;            // 16*96*256*256/4 = 25,165,824
    const int iters  = total4 / (BLOCKS * TPB); // 48, exact (25165824 = 524288*48)
    dualswitch_kernel<<<BLOCKS, TPB, 0, stream>>>(in, out, iters);
}

// Round 3
// 629.797 us; speedup vs baseline: 1.0636x; 1.0636x over previous
//
#include <hip/hip_runtime.h>

// out[b,c,h,w] = x[b,c, h^3, w^3]  (combined adjacent+interlaced perm = reverse
// each block of 4 on both H and W; 256 % 4 == 0 so no tail handling).
// Flat:  out[e] = in[e ^ 0x303].
// float4: out4[t] = reverse_components(in4[t ^ 0xC0]).
//
// Pure HBM stream: 402.7 MB read + 402.7 MB write. Kernel dispatch never shows
// in rocprof top-5 (every slot is a ~253us harness fill) => kernel < 253us;
// most of dur_us is fixed harness reset traffic.
//
// Round-2 post-mortem: nt hints + 48-deep grid-stride loop regressed +61us.
// This version: 4 INDEPENDENT float4/thread (no loop-carried chain, no nt).
// Block covers 4096 contiguous float4 (16 KiB); each wave instruction still
// reads/writes one contiguous 1 KiB segment -> fully coalesced both sides.

#define TPB 256

typedef float f4 __attribute__((ext_vector_type(4)));

__global__ __launch_bounds__(TPB) void dualswitch_kernel(
    const f4* __restrict__ in, f4* __restrict__ out) {
    const int base = blockIdx.x * (TPB * 4) + threadIdx.x;
    // 4 independent loads in flight; XOR 0xC0 flips bits 6,7 (wave-index bits)
    f4 v0 = in[(base          ) ^ 0xC0];
    f4 v1 = in[(base + TPB    ) ^ 0xC0];
    f4 v2 = in[(base + TPB * 2) ^ 0xC0];
    f4 v3 = in[(base + TPB * 3) ^ 0xC0];
    out[base          ] = (f4){v0.w, v0.z, v0.y, v0.x};
    out[base + TPB    ] = (f4){v1.w, v1.z, v1.y, v1.x};
    out[base + TPB * 2] = (f4){v2.w, v2.z, v2.y, v2.x};
    out[base + TPB * 3] = (f4){v3.w, v3.z, v3.y, v3.x};
}

extern "C" void kernel_launch(void* const* d_in, const int* in_sizes, int n_in,
                              void* d_out, int out_size, void* d_ws, size_t ws_size,
                              hipStream_t stream) {
    const f4* in = (const f4*)d_in[0];
    f4* out = (f4*)d_out;
    const int total4 = out_size / 4;        // 25,165,824 float4
    const int blocks = total4 / (TPB * 4);  // 24,576, exact
    dualswitch_kernel<<<blocks, TPB, 0, stream>>>(in, out);
}

// Round 4
// 611.418 us; speedup vs baseline: 1.0956x; 1.0301x over previous
//
#include <hip/hip_runtime.h>

// out[b,c,h,w] = x[b,c, h^3, w^3]  (combined adjacent+interlaced perm = reverse
// each block of 4 on both H and W; 256 % 4 == 0 so no tail handling).
// Flat:  out[e] = in[e ^ 0x303].
// float4: out4[t] = reverse_components(in4[t ^ 0xC0]).
// Both sides coalesced at 16 B/lane; pure HBM-streaming permute.
//
// Session post-mortem (R0-R3): this one-float4-per-thread form is the fastest
// measured (609.4 us). Adding ILP (4 independent float4/thread: +20 us),
// grid-stride x48 + nontemporal hints (+60 us) both regressed. rocprof shows
// the kernel dispatch never enters top-5 (all slots are ~253 us harness
// fills) => kernel < 249 us; dur_us decomposition gives kernel <= ~109 us,
// i.e. at/below the 805 MB full-stream floor thanks to partial L3 write
// absorption. Remaining headroom <= ~6% of dur_us; treat as roofline.

__global__ __launch_bounds__(256) void dualswitch_kernel(
    const float4* __restrict__ in, float4* __restrict__ out) {
    const int t = blockIdx.x * 256 + threadIdx.x;
    const float4 v = in[t ^ 0xC0];              // h ^= 3 (rows within 4-row group)
    out[t] = make_float4(v.w, v.z, v.y, v.x);   // w ^= 3 (reverse inside float4)
}

extern "C" void kernel_launch(void* const* d_in, const int* in_sizes, int n_in,
                              void* d_out, int out_size, void* d_ws, size_t ws_size,
                              hipStream_t stream) {
    const float4* in = (const float4*)d_in[0];
    float4* out = (float4*)d_out;
    const int total4 = out_size / 4;            // 16*96*256*256/4 = 25,165,824
    const int blocks = total4 / 256;            // 98,304, exact
    dualswitch_kernel<<<blocks, 256, 0, stream>>>(in, out);
}